// Round 1
// baseline (419.702 us; speedup 1.0000x reference)
//
#include <hip/hip_runtime.h>

#define N_NODES 50000
#define N_EDGESx 600000
#define E_TOT   (N_EDGESx + N_NODES)   // 650000
#define NEG_SLOPE 0.2f

__device__ __forceinline__ float lrelu(float x) { return x > 0.f ? x : NEG_SLOPE * x; }

// ---------------------------------------------------------------- CSR build
__global__ __launch_bounds__(256) void count_k(const int* __restrict__ ei,
                                               int* __restrict__ counts) {
    int i = blockIdx.x * 256 + threadIdx.x;
    if (i >= E_TOT) return;
    int dst = (i < N_EDGESx) ? ei[N_EDGESx + i] : (i - N_EDGESx);
    atomicAdd(&counts[dst], 1);
}

__global__ __launch_bounds__(1024) void scanA(const int* __restrict__ counts,
                                              int* __restrict__ offs,
                                              int* __restrict__ chunks, int N) {
    __shared__ int sdata[1024];
    int t = threadIdx.x;
    int g = blockIdx.x * 1024 + t;
    int v = (g < N) ? counts[g] : 0;
    sdata[t] = v;
    __syncthreads();
    for (int off = 1; off < 1024; off <<= 1) {
        int x = (t >= off) ? sdata[t - off] : 0;
        __syncthreads();
        sdata[t] += x;
        __syncthreads();
    }
    int incl = sdata[t];
    if (g < N) offs[g] = incl - v;           // exclusive within chunk
    if (t == 1023) chunks[blockIdx.x] = incl;
}

__global__ void scanB(int* chunks, int nch) {
    if (threadIdx.x == 0 && blockIdx.x == 0) {
        int run = 0;
        for (int i = 0; i < nch; ++i) { int c = chunks[i]; chunks[i] = run; run += c; }
    }
}

__global__ __launch_bounds__(1024) void scanC(int* __restrict__ offs,
                                              const int* __restrict__ chunks, int N) {
    int g = blockIdx.x * 1024 + threadIdx.x;
    if (g < N) offs[g] += chunks[blockIdx.x];
}

__global__ __launch_bounds__(256) void scatter_k(const int* __restrict__ ei,
                                                 const int* __restrict__ offs,
                                                 int* __restrict__ cursor,
                                                 int* __restrict__ edge_src,
                                                 int* __restrict__ edge_dst) {
    int i = blockIdx.x * 256 + threadIdx.x;
    if (i >= E_TOT) return;
    int src, dst;
    if (i < N_EDGESx) { src = ei[i]; dst = ei[N_EDGESx + i]; }
    else              { src = dst = i - N_EDGESx; }
    int pos = atomicAdd(&cursor[dst], 1);
    int p = offs[dst] + pos;
    edge_src[p] = src;
    edge_dst[p] = dst;
}

// ---------------------------------------------------------------- GEMM (64x64 tile, 4x4 micro)
template<int KTOT, int NPANELS>
__global__ __launch_bounds__(256, 2) void gemm64(const float* __restrict__ A,
                                                 const float* __restrict__ B,
                                                 float* __restrict__ C, int M) {
    constexpr int LDB = NPANELS * 64;
    __shared__ float As[64][140];   // pad 140: float4-aligned, <=2-way banks on read
    __shared__ float Bs[128][64];
    const int t = threadIdx.x;
    const int mb = blockIdx.x / NPANELS;
    const int panel = blockIdx.x % NPANELS;
    const int row0 = mb * 64;
    const int col0 = panel * 64;
    const int tx = t & 15;
    const int ty = t >> 4;
    float acc[4][4] = {};
    for (int kk = 0; kk < KTOT; kk += 128) {
        __syncthreads();
#pragma unroll
        for (int i = 0; i < 8; ++i) {
            int idx = i * 1024 + t * 4;
            int r = idx >> 7;
            int k = idx & 127;
            float4 v = make_float4(0.f, 0.f, 0.f, 0.f);
            int grow = row0 + r;
            if (grow < M) v = *(const float4*)(A + (size_t)grow * KTOT + kk + k);
            *(float4*)&As[r][k] = v;
            int kb = idx >> 6;
            int cb = idx & 63;
            *(float4*)&Bs[kb][cb] = *(const float4*)(B + (size_t)(kk + kb) * LDB + col0 + cb);
        }
        __syncthreads();
#pragma unroll 4
        for (int k = 0; k < 128; k += 4) {
            float av[4][4], bv[4][4];
#pragma unroll
            for (int i = 0; i < 4; ++i)
                *(float4*)av[i] = *(const float4*)&As[ty * 4 + i][k];
#pragma unroll
            for (int j = 0; j < 4; ++j)
                *(float4*)bv[j] = *(const float4*)&Bs[k + j][tx * 4];
#pragma unroll
            for (int j = 0; j < 4; ++j)
#pragma unroll
                for (int i = 0; i < 4; ++i)
#pragma unroll
                    for (int c = 0; c < 4; ++c)
                        acc[i][c] += av[i][j] * bv[j][c];
        }
    }
#pragma unroll
    for (int i = 0; i < 4; ++i) {
        int grow = row0 + ty * 4 + i;
        if (grow < M)
            *(float4*)(C + (size_t)grow * LDB + col0 + tx * 4) =
                make_float4(acc[i][0], acc[i][1], acc[i][2], acc[i][3]);
    }
}

// ---------------------------------------------------------------- alpha dots
__global__ __launch_bounds__(256) void alpha1_k(const float* __restrict__ h1,
                                                const float* __restrict__ a_src,
                                                const float* __restrict__ a_dst,
                                                float* __restrict__ as1,
                                                float* __restrict__ ad1, int N) {
    int lane = threadIdx.x & 63;
    int n = blockIdx.x * 4 + (threadIdx.x >> 6);
    if (n >= N) return;
    const float* hr = h1 + (size_t)n * 256;
#pragma unroll
    for (int h = 0; h < 4; ++h) {
        float hv = hr[h * 64 + lane];
        float s = hv * a_src[h * 64 + lane];
        float d = hv * a_dst[h * 64 + lane];
#pragma unroll
        for (int i = 0; i < 6; ++i) {
            s += __shfl_xor(s, 1 << i);
            d += __shfl_xor(d, 1 << i);
        }
        if (lane == 0) { as1[n * 4 + h] = s; ad1[n * 4 + h] = d; }
    }
}

__global__ __launch_bounds__(256) void alpha2_k(const float* __restrict__ h2,
                                                const float* __restrict__ a_src,
                                                const float* __restrict__ a_dst,
                                                float* __restrict__ as2,
                                                float* __restrict__ ad2, int N) {
    int lane = threadIdx.x & 63;
    int n = blockIdx.x * 4 + (threadIdx.x >> 6);
    if (n >= N) return;
    float hv = h2[(size_t)n * 64 + lane];
    float s = hv * a_src[lane];
    float d = hv * a_dst[lane];
#pragma unroll
    for (int i = 0; i < 6; ++i) {
        s += __shfl_xor(s, 1 << i);
        d += __shfl_xor(d, 1 << i);
    }
    if (lane == 0) { as2[n] = s; ad2[n] = d; }
}

// ---------------------------------------------------------------- edge scores
__global__ __launch_bounds__(256) void e1_k(const int* __restrict__ edge_src,
                                            const int* __restrict__ edge_dst,
                                            const float* __restrict__ as1,
                                            const float* __restrict__ ad1,
                                            float* __restrict__ e_buf) {
    int p = blockIdx.x * 256 + threadIdx.x;
    if (p >= E_TOT) return;
    int s = edge_src[p], d = edge_dst[p];
    float4 es = *(const float4*)(as1 + (size_t)s * 4);
    float4 ed = *(const float4*)(ad1 + (size_t)d * 4);
    float4 e;
    e.x = lrelu(es.x + ed.x);
    e.y = lrelu(es.y + ed.y);
    e.z = lrelu(es.z + ed.z);
    e.w = lrelu(es.w + ed.w);
    *(float4*)(e_buf + (size_t)p * 4) = e;
}

__global__ __launch_bounds__(256) void e2_k(const int* __restrict__ edge_src,
                                            const int* __restrict__ edge_dst,
                                            const float* __restrict__ as2,
                                            const float* __restrict__ ad2,
                                            float* __restrict__ e_buf) {
    int p = blockIdx.x * 256 + threadIdx.x;
    if (p >= E_TOT) return;
    e_buf[p] = lrelu(as2[edge_src[p]] + ad2[edge_dst[p]]);
}

// ---------------------------------------------------------------- softmax + aggregate
__global__ __launch_bounds__(256) void agg1_k(const float* __restrict__ h1,
                                              const float* __restrict__ e_buf,
                                              const int* __restrict__ edge_src,
                                              const int* __restrict__ offs,
                                              const int* __restrict__ counts,
                                              const float* __restrict__ b1,
                                              float* __restrict__ out1, int N) {
    int lane = threadIdx.x & 63;
    int n = blockIdx.x * 4 + (threadIdx.x >> 6);
    if (n >= N) return;
    int start = offs[n];
    int end = start + counts[n];
    int h4 = lane & 3;
    float m = -1e30f, s = 0.f;
    for (int p = start + (lane >> 2); p < end; p += 16) {
        float e = e_buf[(size_t)p * 4 + h4];
        float nm = fmaxf(m, e);
        s = s * __expf(m - nm) + __expf(e - nm);
        m = nm;
    }
#pragma unroll
    for (int i = 0; i < 4; ++i) {                 // reduce over lanes with same head
        int msk = 4 << i;
        float om = __shfl_xor(m, msk);
        float os = __shfl_xor(s, msk);
        float nm = fmaxf(m, om);
        s = s * __expf(m - nm) + os * __expf(om - nm);
        m = nm;
    }
    float mh0 = __shfl(m, 0), mh1 = __shfl(m, 1), mh2 = __shfl(m, 2), mh3 = __shfl(m, 3);
    float rs0 = 1.f / (__shfl(s, 0) + 1e-16f);
    float rs1 = 1.f / (__shfl(s, 1) + 1e-16f);
    float rs2 = 1.f / (__shfl(s, 2) + 1e-16f);
    float rs3 = 1.f / (__shfl(s, 3) + 1e-16f);
    float acc0 = 0.f, acc1 = 0.f, acc2 = 0.f, acc3 = 0.f;
    for (int p = start; p < end; ++p) {
        int src = edge_src[p];
        float4 ev = *(const float4*)(e_buf + (size_t)p * 4);
        float w0 = __expf(ev.x - mh0) * rs0;
        float w1 = __expf(ev.y - mh1) * rs1;
        float w2 = __expf(ev.z - mh2) * rs2;
        float w3 = __expf(ev.w - mh3) * rs3;
        const float* hr = h1 + (size_t)src * 256;
        acc0 += hr[lane] * w0;
        acc1 += hr[64 + lane] * w1;
        acc2 += hr[128 + lane] * w2;
        acc3 += hr[192 + lane] * w3;
    }
    float* o = out1 + (size_t)n * 256;
    o[lane]       = fmaxf(acc0 + b1[lane], 0.f);
    o[64 + lane]  = fmaxf(acc1 + b1[64 + lane], 0.f);
    o[128 + lane] = fmaxf(acc2 + b1[128 + lane], 0.f);
    o[192 + lane] = fmaxf(acc3 + b1[192 + lane], 0.f);
}

__global__ __launch_bounds__(256) void agg2_k(const float* __restrict__ h2,
                                              const float* __restrict__ e_buf,
                                              const int* __restrict__ edge_src,
                                              const int* __restrict__ offs,
                                              const int* __restrict__ counts,
                                              const float* __restrict__ b2,
                                              float* __restrict__ out2, int N) {
    int lane = threadIdx.x & 63;
    int n = blockIdx.x * 4 + (threadIdx.x >> 6);
    if (n >= N) return;
    int start = offs[n];
    int end = start + counts[n];
    float m = -1e30f, s = 0.f;
    for (int p = start + lane; p < end; p += 64) {
        float e = e_buf[p];
        float nm = fmaxf(m, e);
        s = s * __expf(m - nm) + __expf(e - nm);
        m = nm;
    }
#pragma unroll
    for (int i = 0; i < 6; ++i) {
        int msk = 1 << i;
        float om = __shfl_xor(m, msk);
        float os = __shfl_xor(s, msk);
        float nm = fmaxf(m, om);
        s = s * __expf(m - nm) + os * __expf(om - nm);
        m = nm;
    }
    float rs = 1.f / (s + 1e-16f);
    float acc = 0.f;
    for (int p = start; p < end; ++p) {
        int src = edge_src[p];
        float w = __expf(e_buf[p] - m) * rs;
        acc += h2[(size_t)src * 64 + lane] * w;
    }
    out2[(size_t)n * 64 + lane] = fmaxf(acc + b2[lane], 0.f);
}

// ---------------------------------------------------------------- classifier head
__global__ __launch_bounds__(256) void cls_k(const float* __restrict__ hin,
                                             const float* __restrict__ Wc1,
                                             const float* __restrict__ bc1,
                                             const float* __restrict__ Wc2,
                                             const float* __restrict__ bc2,
                                             float* __restrict__ out, int N) {
    __shared__ float W1s[64 * 32];
    __shared__ float W2s[64];
    __shared__ float b1s[32];
    __shared__ float b2s[2];
    __shared__ float z[8][33];
    int t = threadIdx.x;
    for (int i = t; i < 2048; i += 256) W1s[i] = Wc1[i];
    if (t < 64) W2s[t] = Wc2[t];
    if (t < 32) b1s[t] = bc1[t];
    if (t < 2)  b2s[t] = bc2[t];
    __syncthreads();
    int nl = t >> 5, j = t & 31;
    int n = blockIdx.x * 8 + nl;
    float acc = b1s[j];
    if (n < N) {
        const float* hr = hin + (size_t)n * 64;
#pragma unroll 8
        for (int l = 0; l < 64; ++l) acc += hr[l] * W1s[l * 32 + j];
    }
    z[nl][j] = fmaxf(acc, 0.f);
    __syncthreads();
    if (j < 2 && n < N) {
        float o = b2s[j];
#pragma unroll
        for (int q = 0; q < 32; ++q) o += z[nl][q] * W2s[q * 2 + j];
        out[(size_t)n * 2 + j] = o;
    }
}

// ---------------------------------------------------------------- launch
extern "C" void kernel_launch(void* const* d_in, const int* in_sizes, int n_in,
                              void* d_out, int out_size, void* d_ws, size_t ws_size,
                              hipStream_t stream) {
    const float* x      = (const float*)d_in[0];
    const int*   ei     = (const int*)d_in[1];
    const float* W1     = (const float*)d_in[2];
    const float* a_src1 = (const float*)d_in[3];
    const float* a_dst1 = (const float*)d_in[4];
    const float* b1     = (const float*)d_in[5];
    const float* W2     = (const float*)d_in[6];
    const float* a_src2 = (const float*)d_in[7];
    const float* a_dst2 = (const float*)d_in[8];
    const float* b2     = (const float*)d_in[9];
    const float* Wc1    = (const float*)d_in[10];
    const float* bc1    = (const float*)d_in[11];
    const float* Wc2    = (const float*)d_in[12];
    const float* bc2    = (const float*)d_in[13];

    char* ws = (char*)d_ws;
    size_t off = 0;
    auto alloc = [&](size_t bytes) -> void* {
        void* p = ws + off;
        off += (bytes + 255) & ~(size_t)255;
        return p;
    };
    int*   counts   = (int*)alloc((size_t)N_NODES * 4);
    int*   cursor   = (int*)alloc((size_t)N_NODES * 4);
    int*   offs     = (int*)alloc((size_t)N_NODES * 4);
    int*   chunks   = (int*)alloc(256);
    int*   edge_src = (int*)alloc((size_t)E_TOT * 4);
    int*   edge_dst = (int*)alloc((size_t)E_TOT * 4);
    float* e_buf    = (float*)alloc((size_t)E_TOT * 4 * 4);
    float* as1      = (float*)alloc((size_t)N_NODES * 16);
    float* ad1      = (float*)alloc((size_t)N_NODES * 16);
    float* as2      = (float*)alloc((size_t)N_NODES * 4);
    float* ad2      = (float*)alloc((size_t)N_NODES * 4);
    float* h1       = (float*)alloc((size_t)N_NODES * 256 * 4);  // reused as h2
    float* out1     = (float*)alloc((size_t)N_NODES * 256 * 4);  // reused as out2
    float* h2   = h1;
    float* out2 = out1;

    const int EB = (E_TOT + 255) / 256;
    const int NCH = (N_NODES + 1023) / 1024;  // 49
    const int MB = (N_NODES + 63) / 64;       // 782

    hipMemsetAsync(counts, 0, (size_t)N_NODES * 4, stream);
    hipMemsetAsync(cursor, 0, (size_t)N_NODES * 4, stream);

    count_k<<<EB, 256, 0, stream>>>(ei, counts);
    scanA<<<NCH, 1024, 0, stream>>>(counts, offs, chunks, N_NODES);
    scanB<<<1, 64, 0, stream>>>(chunks, NCH);
    scanC<<<NCH, 1024, 0, stream>>>(offs, chunks, N_NODES);
    scatter_k<<<EB, 256, 0, stream>>>(ei, offs, cursor, edge_src, edge_dst);

    gemm64<128, 4><<<MB * 4, 256, 0, stream>>>(x, W1, h1, N_NODES);
    alpha1_k<<<(N_NODES + 3) / 4, 256, 0, stream>>>(h1, a_src1, a_dst1, as1, ad1, N_NODES);
    e1_k<<<EB, 256, 0, stream>>>(edge_src, edge_dst, as1, ad1, e_buf);
    agg1_k<<<(N_NODES + 3) / 4, 256, 0, stream>>>(h1, e_buf, edge_src, offs, counts, b1, out1, N_NODES);

    gemm64<256, 1><<<MB, 256, 0, stream>>>(out1, W2, h2, N_NODES);
    alpha2_k<<<(N_NODES + 3) / 4, 256, 0, stream>>>(h2, a_src2, a_dst2, as2, ad2, N_NODES);
    e2_k<<<EB, 256, 0, stream>>>(edge_src, edge_dst, as2, ad2, e_buf);
    agg2_k<<<(N_NODES + 3) / 4, 256, 0, stream>>>(h2, e_buf, edge_src, offs, counts, b2, out2, N_NODES);

    cls_k<<<N_NODES / 8, 256, 0, stream>>>(out2, Wc1, bc1, Wc2, bc2, (float*)d_out, N_NODES);
}

// Round 4
// 356.490 us; speedup vs baseline: 1.1773x; 1.1773x over previous
//
#include <hip/hip_runtime.h>
#include <hip/hip_fp16.h>

#define N_NODES 50000
#define N_EDGESx 600000
#define E_TOT   (N_EDGESx + N_NODES)   // 650000
#define NEG_SLOPE 0.2f

__device__ __forceinline__ float lrelu(float x) { return x > 0.f ? x : NEG_SLOPE * x; }

// ---------------------------------------------------------------- CSR build
__global__ __launch_bounds__(256) void count_k(const int* __restrict__ ei,
                                               int* __restrict__ counts) {
    int i = blockIdx.x * 256 + threadIdx.x;
    if (i >= E_TOT) return;
    int dst = (i < N_EDGESx) ? ei[N_EDGESx + i] : (i - N_EDGESx);
    atomicAdd(&counts[dst], 1);
}

__global__ __launch_bounds__(1024) void scanA(const int* __restrict__ counts,
                                              int* __restrict__ offs,
                                              int* __restrict__ chunks, int N) {
    __shared__ int sdata[1024];
    int t = threadIdx.x;
    int g = blockIdx.x * 1024 + t;
    int v = (g < N) ? counts[g] : 0;
    sdata[t] = v;
    __syncthreads();
    for (int off = 1; off < 1024; off <<= 1) {
        int x = (t >= off) ? sdata[t - off] : 0;
        __syncthreads();
        sdata[t] += x;
        __syncthreads();
    }
    int incl = sdata[t];
    if (g < N) offs[g] = incl - v;           // exclusive within chunk
    if (t == 1023) chunks[blockIdx.x] = incl;
}

// wave-parallel scan over <=64 chunk totals (was a serial 49-step pointer chase)
__global__ void scanB(int* chunks, int nch) {
    int lane = threadIdx.x & 63;
    int orig = (lane < nch) ? chunks[lane] : 0;
    int v = orig;
#pragma unroll
    for (int off = 1; off < 64; off <<= 1) {
        int u = __shfl_up(v, off);
        if (lane >= off) v += u;
    }
    if (lane < nch) chunks[lane] = v - orig;  // exclusive
}

__global__ __launch_bounds__(1024) void scanC(int* __restrict__ offs,
                                              const int* __restrict__ chunks, int N) {
    int g = blockIdx.x * 1024 + threadIdx.x;
    if (g < N) offs[g] += chunks[blockIdx.x];
}

__global__ __launch_bounds__(256) void scatter_k(const int* __restrict__ ei,
                                                 const int* __restrict__ offs,
                                                 int* __restrict__ cursor,
                                                 int* __restrict__ edge_src,
                                                 int* __restrict__ edge_dst) {
    int i = blockIdx.x * 256 + threadIdx.x;
    if (i >= E_TOT) return;
    int src, dst;
    if (i < N_EDGESx) { src = ei[i]; dst = ei[N_EDGESx + i]; }
    else              { src = dst = i - N_EDGESx; }
    int pos = atomicAdd(&cursor[dst], 1);
    int p = offs[dst] + pos;
    edge_src[p] = src;
    edge_dst[p] = dst;
}

// ---------------------------------------------------------------- GEMM (64x64 tile, 4x4 micro)
template<int KTOT, int NPANELS, typename OutT>
__global__ __launch_bounds__(256, 2) void gemm64(const float* __restrict__ A,
                                                 const float* __restrict__ B,
                                                 OutT* __restrict__ C, int M) {
    constexpr int LDB = NPANELS * 64;
    __shared__ float As[64][140];   // pad 140: float4-aligned, <=2-way banks on read
    __shared__ float Bs[128][64];
    const int t = threadIdx.x;
    const int mb = blockIdx.x / NPANELS;
    const int panel = blockIdx.x % NPANELS;
    const int row0 = mb * 64;
    const int col0 = panel * 64;
    const int tx = t & 15;
    const int ty = t >> 4;
    float acc[4][4] = {};
    for (int kk = 0; kk < KTOT; kk += 128) {
        __syncthreads();
#pragma unroll
        for (int i = 0; i < 8; ++i) {
            int idx = i * 1024 + t * 4;
            int r = idx >> 7;
            int k = idx & 127;
            float4 v = make_float4(0.f, 0.f, 0.f, 0.f);
            int grow = row0 + r;
            if (grow < M) v = *(const float4*)(A + (size_t)grow * KTOT + kk + k);
            *(float4*)&As[r][k] = v;
            int kb = idx >> 6;
            int cb = idx & 63;
            *(float4*)&Bs[kb][cb] = *(const float4*)(B + (size_t)(kk + kb) * LDB + col0 + cb);
        }
        __syncthreads();
#pragma unroll 4
        for (int k = 0; k < 128; k += 4) {
            float av[4][4], bv[4][4];
#pragma unroll
            for (int i = 0; i < 4; ++i)
                *(float4*)av[i] = *(const float4*)&As[ty * 4 + i][k];
#pragma unroll
            for (int j = 0; j < 4; ++j)
                *(float4*)bv[j] = *(const float4*)&Bs[k + j][tx * 4];
#pragma unroll
            for (int j = 0; j < 4; ++j)
#pragma unroll
                for (int i = 0; i < 4; ++i)
#pragma unroll
                    for (int c = 0; c < 4; ++c)
                        acc[i][c] += av[i][j] * bv[j][c];
        }
    }
#pragma unroll
    for (int i = 0; i < 4; ++i) {
        int grow = row0 + ty * 4 + i;
        if (grow >= M) continue;
        if constexpr (sizeof(OutT) == 2) {
            __half hv[4];
#pragma unroll
            for (int c = 0; c < 4; ++c) hv[c] = __float2half(acc[i][c]);
            *(float2*)(C + (size_t)grow * LDB + col0 + tx * 4) = *(float2*)hv;
        } else {
            *(float4*)(C + (size_t)grow * LDB + col0 + tx * 4) =
                make_float4(acc[i][0], acc[i][1], acc[i][2], acc[i][3]);
        }
    }
}

// ---------------------------------------------------------------- alpha dots
__global__ __launch_bounds__(256) void alpha1_k(const __half* __restrict__ h1,
                                                const float* __restrict__ a_src,
                                                const float* __restrict__ a_dst,
                                                float* __restrict__ as1,
                                                float* __restrict__ ad1, int N) {
    int lane = threadIdx.x & 63;
    int n = blockIdx.x * 4 + (threadIdx.x >> 6);
    if (n >= N) return;
    const __half* hr = h1 + (size_t)n * 256;
#pragma unroll
    for (int h = 0; h < 4; ++h) {
        float hv = __half2float(hr[h * 64 + lane]);
        float s = hv * a_src[h * 64 + lane];
        float d = hv * a_dst[h * 64 + lane];
#pragma unroll
        for (int i = 0; i < 6; ++i) {
            s += __shfl_xor(s, 1 << i);
            d += __shfl_xor(d, 1 << i);
        }
        if (lane == 0) { as1[n * 4 + h] = s; ad1[n * 4 + h] = d; }
    }
}

__global__ __launch_bounds__(256) void alpha2_k(const float* __restrict__ h2,
                                                const float* __restrict__ a_src,
                                                const float* __restrict__ a_dst,
                                                float* __restrict__ as2,
                                                float* __restrict__ ad2, int N) {
    int lane = threadIdx.x & 63;
    int n = blockIdx.x * 4 + (threadIdx.x >> 6);
    if (n >= N) return;
    float hv = h2[(size_t)n * 64 + lane];
    float s = hv * a_src[lane];
    float d = hv * a_dst[lane];
#pragma unroll
    for (int i = 0; i < 6; ++i) {
        s += __shfl_xor(s, 1 << i);
        d += __shfl_xor(d, 1 << i);
    }
    if (lane == 0) { as2[n] = s; ad2[n] = d; }
}

// ---------------------------------------------------------------- edge scores
__global__ __launch_bounds__(256) void e1_k(const int* __restrict__ edge_src,
                                            const int* __restrict__ edge_dst,
                                            const float* __restrict__ as1,
                                            const float* __restrict__ ad1,
                                            float* __restrict__ e_buf) {
    int p = blockIdx.x * 256 + threadIdx.x;
    if (p >= E_TOT) return;
    int s = edge_src[p], d = edge_dst[p];
    float4 es = *(const float4*)(as1 + (size_t)s * 4);
    float4 ed = *(const float4*)(ad1 + (size_t)d * 4);
    float4 e;
    e.x = lrelu(es.x + ed.x);
    e.y = lrelu(es.y + ed.y);
    e.z = lrelu(es.z + ed.z);
    e.w = lrelu(es.w + ed.w);
    *(float4*)(e_buf + (size_t)p * 4) = e;
}

__global__ __launch_bounds__(256) void e2_k(const int* __restrict__ edge_src,
                                            const int* __restrict__ edge_dst,
                                            const float* __restrict__ as2,
                                            const float* __restrict__ ad2,
                                            float* __restrict__ e_buf) {
    int p = blockIdx.x * 256 + threadIdx.x;
    if (p >= E_TOT) return;
    e_buf[p] = lrelu(as2[edge_src[p]] + ad2[edge_dst[p]]);
}

// ---------------------------------------------------------------- softmax + aggregate
__global__ __launch_bounds__(256) void agg1_k(const __half* __restrict__ h1,
                                              const float* __restrict__ e_buf,
                                              const int* __restrict__ edge_src,
                                              const int* __restrict__ offs,
                                              const int* __restrict__ counts,
                                              const float* __restrict__ b1,
                                              float* __restrict__ out1, int N) {
    int lane = threadIdx.x & 63;
    int n = blockIdx.x * 4 + (threadIdx.x >> 6);
    if (n >= N) return;
    int start = offs[n];
    int end = start + counts[n];
    int h4 = lane & 3;
    float m = -1e30f, s = 0.f;
    for (int p = start + (lane >> 2); p < end; p += 16) {
        float e = e_buf[(size_t)p * 4 + h4];
        float nm = fmaxf(m, e);
        s = s * __expf(m - nm) + __expf(e - nm);
        m = nm;
    }
#pragma unroll
    for (int i = 0; i < 4; ++i) {                 // reduce over lanes with same head
        int msk = 4 << i;
        float om = __shfl_xor(m, msk);
        float os = __shfl_xor(s, msk);
        float nm = fmaxf(m, om);
        s = s * __expf(m - nm) + os * __expf(om - nm);
        m = nm;
    }
    float mh0 = __shfl(m, 0), mh1 = __shfl(m, 1), mh2 = __shfl(m, 2), mh3 = __shfl(m, 3);
    float rs0 = 1.f / (__shfl(s, 0) + 1e-16f);
    float rs1 = 1.f / (__shfl(s, 1) + 1e-16f);
    float rs2 = 1.f / (__shfl(s, 2) + 1e-16f);
    float rs3 = 1.f / (__shfl(s, 3) + 1e-16f);
    float acc0 = 0.f, acc1 = 0.f, acc2 = 0.f, acc3 = 0.f;
    int p = start;
    for (; p + 1 < end; p += 2) {                  // 2-edge unroll: 2x loads in flight
        int s0 = edge_src[p], s1 = edge_src[p + 1];
        float4 ev0 = *(const float4*)(e_buf + (size_t)p * 4);
        float4 ev1 = *(const float4*)(e_buf + (size_t)(p + 1) * 4);
        const __half* r0 = h1 + (size_t)s0 * 256;
        const __half* r1 = h1 + (size_t)s1 * 256;
        float a00 = __half2float(r0[lane]);
        float a01 = __half2float(r0[64 + lane]);
        float a02 = __half2float(r0[128 + lane]);
        float a03 = __half2float(r0[192 + lane]);
        float a10 = __half2float(r1[lane]);
        float a11 = __half2float(r1[64 + lane]);
        float a12 = __half2float(r1[128 + lane]);
        float a13 = __half2float(r1[192 + lane]);
        float w00 = __expf(ev0.x - mh0) * rs0, w10 = __expf(ev1.x - mh0) * rs0;
        float w01 = __expf(ev0.y - mh1) * rs1, w11 = __expf(ev1.y - mh1) * rs1;
        float w02 = __expf(ev0.z - mh2) * rs2, w12 = __expf(ev1.z - mh2) * rs2;
        float w03 = __expf(ev0.w - mh3) * rs3, w13 = __expf(ev1.w - mh3) * rs3;
        acc0 += a00 * w00 + a10 * w10;
        acc1 += a01 * w01 + a11 * w11;
        acc2 += a02 * w02 + a12 * w12;
        acc3 += a03 * w03 + a13 * w13;
    }
    if (p < end) {
        int s0 = edge_src[p];
        float4 ev0 = *(const float4*)(e_buf + (size_t)p * 4);
        const __half* r0 = h1 + (size_t)s0 * 256;
        acc0 += __half2float(r0[lane])       * (__expf(ev0.x - mh0) * rs0);
        acc1 += __half2float(r0[64 + lane])  * (__expf(ev0.y - mh1) * rs1);
        acc2 += __half2float(r0[128 + lane]) * (__expf(ev0.z - mh2) * rs2);
        acc3 += __half2float(r0[192 + lane]) * (__expf(ev0.w - mh3) * rs3);
    }
    float* o = out1 + (size_t)n * 256;
    o[lane]       = fmaxf(acc0 + b1[lane], 0.f);
    o[64 + lane]  = fmaxf(acc1 + b1[64 + lane], 0.f);
    o[128 + lane] = fmaxf(acc2 + b1[128 + lane], 0.f);
    o[192 + lane] = fmaxf(acc3 + b1[192 + lane], 0.f);
}

__global__ __launch_bounds__(256) void agg2_k(const float* __restrict__ h2,
                                              const float* __restrict__ e_buf,
                                              const int* __restrict__ edge_src,
                                              const int* __restrict__ offs,
                                              const int* __restrict__ counts,
                                              const float* __restrict__ b2,
                                              float* __restrict__ out2, int N) {
    int lane = threadIdx.x & 63;
    int n = blockIdx.x * 4 + (threadIdx.x >> 6);
    if (n >= N) return;
    int start = offs[n];
    int end = start + counts[n];
    float m = -1e30f, s = 0.f;
    for (int p = start + lane; p < end; p += 64) {
        float e = e_buf[p];
        float nm = fmaxf(m, e);
        s = s * __expf(m - nm) + __expf(e - nm);
        m = nm;
    }
#pragma unroll
    for (int i = 0; i < 6; ++i) {
        int msk = 1 << i;
        float om = __shfl_xor(m, msk);
        float os = __shfl_xor(s, msk);
        float nm = fmaxf(m, om);
        s = s * __expf(m - nm) + os * __expf(om - nm);
        m = nm;
    }
    float rs = 1.f / (s + 1e-16f);
    float acc = 0.f;
    int p = start;
    for (; p + 1 < end; p += 2) {
        int s0 = edge_src[p], s1 = edge_src[p + 1];
        float e0 = e_buf[p], e1 = e_buf[p + 1];
        float v0 = h2[(size_t)s0 * 64 + lane];
        float v1 = h2[(size_t)s1 * 64 + lane];
        acc += v0 * (__expf(e0 - m) * rs) + v1 * (__expf(e1 - m) * rs);
    }
    if (p < end) {
        acc += h2[(size_t)edge_src[p] * 64 + lane] * (__expf(e_buf[p] - m) * rs);
    }
    out2[(size_t)n * 64 + lane] = fmaxf(acc + b2[lane], 0.f);
}

// ---------------------------------------------------------------- classifier head
__global__ __launch_bounds__(256) void cls_k(const float* __restrict__ hin,
                                             const float* __restrict__ Wc1,
                                             const float* __restrict__ bc1,
                                             const float* __restrict__ Wc2,
                                             const float* __restrict__ bc2,
                                             float* __restrict__ out, int N) {
    __shared__ float W1s[64 * 32];
    __shared__ float W2s[64];
    __shared__ float b1s[32];
    __shared__ float b2s[2];
    __shared__ float z[8][33];
    int t = threadIdx.x;
    for (int i = t; i < 2048; i += 256) W1s[i] = Wc1[i];
    if (t < 64) W2s[t] = Wc2[t];
    if (t < 32) b1s[t] = bc1[t];
    if (t < 2)  b2s[t] = bc2[t];
    __syncthreads();
    int nl = t >> 5, j = t & 31;
    int n = blockIdx.x * 8 + nl;
    float acc = b1s[j];
    if (n < N) {
        const float* hr = hin + (size_t)n * 64;
#pragma unroll 8
        for (int l = 0; l < 64; ++l) acc += hr[l] * W1s[l * 32 + j];
    }
    z[nl][j] = fmaxf(acc, 0.f);
    __syncthreads();
    if (j < 2 && n < N) {
        float o = b2s[j];
#pragma unroll
        for (int q = 0; q < 32; ++q) o += z[nl][q] * W2s[q * 2 + j];
        out[(size_t)n * 2 + j] = o;
    }
}

// ---------------------------------------------------------------- launch
extern "C" void kernel_launch(void* const* d_in, const int* in_sizes, int n_in,
                              void* d_out, int out_size, void* d_ws, size_t ws_size,
                              hipStream_t stream) {
    const float* x      = (const float*)d_in[0];
    const int*   ei     = (const int*)d_in[1];
    const float* W1     = (const float*)d_in[2];
    const float* a_src1 = (const float*)d_in[3];
    const float* a_dst1 = (const float*)d_in[4];
    const float* b1     = (const float*)d_in[5];
    const float* W2     = (const float*)d_in[6];
    const float* a_src2 = (const float*)d_in[7];
    const float* a_dst2 = (const float*)d_in[8];
    const float* b2     = (const float*)d_in[9];
    const float* Wc1    = (const float*)d_in[10];
    const float* bc1    = (const float*)d_in[11];
    const float* Wc2    = (const float*)d_in[12];
    const float* bc2    = (const float*)d_in[13];

    char* ws = (char*)d_ws;
    size_t off = 0;
    auto alloc = [&](size_t bytes) -> void* {
        void* p = ws + off;
        off += (bytes + 255) & ~(size_t)255;
        return p;
    };
    int*    counts   = (int*)alloc((size_t)N_NODES * 4);
    int*    cursor   = (int*)alloc((size_t)N_NODES * 4);
    int*    offs     = (int*)alloc((size_t)N_NODES * 4);
    int*    chunks   = (int*)alloc(256);
    int*    edge_src = (int*)alloc((size_t)E_TOT * 4);
    int*    edge_dst = (int*)alloc((size_t)E_TOT * 4);
    float*  e_buf    = (float*)alloc((size_t)E_TOT * 4 * 4);
    float*  as1      = (float*)alloc((size_t)N_NODES * 16);
    float*  ad1      = (float*)alloc((size_t)N_NODES * 16);
    float*  as2      = (float*)alloc((size_t)N_NODES * 4);
    float*  ad2      = (float*)alloc((size_t)N_NODES * 4);
    __half* h1h      = (__half*)alloc((size_t)N_NODES * 256 * 4);  // fp16 used; slot reused as fp32 h2
    float*  out1     = (float*)alloc((size_t)N_NODES * 256 * 4);   // reused as out2
    float*  h2   = (float*)h1h;   // 12.8 MB fp32, fits in the 51.2 MB slot
    float*  out2 = out1;

    const int EB = (E_TOT + 255) / 256;
    const int NCH = (N_NODES + 1023) / 1024;  // 49
    const int MB = (N_NODES + 63) / 64;       // 782

    hipMemsetAsync(counts, 0, (size_t)N_NODES * 4, stream);
    hipMemsetAsync(cursor, 0, (size_t)N_NODES * 4, stream);

    count_k<<<EB, 256, 0, stream>>>(ei, counts);
    scanA<<<NCH, 1024, 0, stream>>>(counts, offs, chunks, N_NODES);
    scanB<<<1, 64, 0, stream>>>(chunks, NCH);
    scanC<<<NCH, 1024, 0, stream>>>(offs, chunks, N_NODES);
    scatter_k<<<EB, 256, 0, stream>>>(ei, offs, cursor, edge_src, edge_dst);

    gemm64<128, 4, __half><<<MB * 4, 256, 0, stream>>>(x, W1, h1h, N_NODES);
    alpha1_k<<<(N_NODES + 3) / 4, 256, 0, stream>>>(h1h, a_src1, a_dst1, as1, ad1, N_NODES);
    e1_k<<<EB, 256, 0, stream>>>(edge_src, edge_dst, as1, ad1, e_buf);
    agg1_k<<<(N_NODES + 3) / 4, 256, 0, stream>>>(h1h, e_buf, edge_src, offs, counts, b1, out1, N_NODES);

    gemm64<256, 1, float><<<MB, 256, 0, stream>>>(out1, W2, h2, N_NODES);
    alpha2_k<<<(N_NODES + 3) / 4, 256, 0, stream>>>(h2, a_src2, a_dst2, as2, ad2, N_NODES);
    e2_k<<<EB, 256, 0, stream>>>(edge_src, edge_dst, as2, ad2, e_buf);
    agg2_k<<<(N_NODES + 3) / 4, 256, 0, stream>>>(h2, e_buf, edge_src, offs, counts, b2, out2, N_NODES);

    cls_k<<<N_NODES / 8, 256, 0, stream>>>(out2, Wc1, bc1, Wc2, bc2, (float*)d_out, N_NODES);
}

// Round 5
// 310.020 us; speedup vs baseline: 1.3538x; 1.1499x over previous
//
#include <hip/hip_runtime.h>
#include <hip/hip_fp16.h>

#define N_NODES 50000
#define N_EDGESx 600000
#define E_TOT   (N_EDGESx + N_NODES)   // 650000
#define NEG_SLOPE 0.2f

typedef _Float16 f16x4 __attribute__((ext_vector_type(4)));
typedef float f32x4 __attribute__((ext_vector_type(4)));

__device__ __forceinline__ float lrelu(float x) { return x > 0.f ? x : NEG_SLOPE * x; }

// ---------------------------------------------------------------- CSR build
__global__ __launch_bounds__(256) void count_k(const int* __restrict__ ei,
                                               int* __restrict__ counts) {
    int i = blockIdx.x * 256 + threadIdx.x;
    if (i >= E_TOT) return;
    int dst = (i < N_EDGESx) ? ei[N_EDGESx + i] : (i - N_EDGESx);
    atomicAdd(&counts[dst], 1);
}

__global__ __launch_bounds__(1024) void scanA(const int* __restrict__ counts,
                                              int* __restrict__ offs,
                                              int* __restrict__ chunks, int N) {
    __shared__ int sdata[1024];
    int t = threadIdx.x;
    int g = blockIdx.x * 1024 + t;
    int v = (g < N) ? counts[g] : 0;
    sdata[t] = v;
    __syncthreads();
    for (int off = 1; off < 1024; off <<= 1) {
        int x = (t >= off) ? sdata[t - off] : 0;
        __syncthreads();
        sdata[t] += x;
        __syncthreads();
    }
    int incl = sdata[t];
    if (g < N) offs[g] = incl - v;           // exclusive within chunk
    if (t == 1023) chunks[blockIdx.x] = incl;
}

// wave-parallel scan over <=64 chunk totals
__global__ void scanB(int* chunks, int nch) {
    int lane = threadIdx.x & 63;
    int orig = (lane < nch) ? chunks[lane] : 0;
    int v = orig;
#pragma unroll
    for (int off = 1; off < 64; off <<= 1) {
        int u = __shfl_up(v, off);
        if (lane >= off) v += u;
    }
    if (lane < nch) chunks[lane] = v - orig;  // exclusive
}

__global__ __launch_bounds__(1024) void scanC(int* __restrict__ offs,
                                              const int* __restrict__ chunks, int N) {
    int g = blockIdx.x * 1024 + threadIdx.x;
    if (g < N) offs[g] += chunks[blockIdx.x];
}

__global__ __launch_bounds__(256) void scatter_k(const int* __restrict__ ei,
                                                 const int* __restrict__ offs,
                                                 int* __restrict__ cursor,
                                                 int* __restrict__ edge_src,
                                                 int* __restrict__ edge_dst) {
    int i = blockIdx.x * 256 + threadIdx.x;
    if (i >= E_TOT) return;
    int src, dst;
    if (i < N_EDGESx) { src = ei[i]; dst = ei[N_EDGESx + i]; }
    else              { src = dst = i - N_EDGESx; }
    int pos = atomicAdd(&cursor[dst], 1);
    int p = offs[dst] + pos;
    edge_src[p] = src;
    edge_dst[p] = dst;
}

// ---------------------------------------------------------------- MFMA GEMM
// C[M x N] (fp16) = A[M x K] @ B[K x N], A fp32 or fp16, B fp32.
// Block: 256 thr / 4 waves, BM=64 rows, all N cols, whole K staged in LDS fp16.
// LDS layout: rows of K halfs, 16B-chunk XOR swizzle (chunk ^= row&15) ->
// frag ds_read_b64 conflicts <=4-way. B stored transposed [n][k].
// MFMA: v_mfma_f32_16x16x16_f16 (verified layout: A[l&15][4*(l>>4)+i],
// B[4*(l>>4)+i][l&15], D row=4*(l>>4)+q col=l&15 per m89).
template<int K, int N, int CPW, typename AT>
__global__ __launch_bounds__(256, 2) void gemm_mfma(const AT* __restrict__ A,
                                                    const float* __restrict__ B,
                                                    _Float16* __restrict__ C, int M) {
    __shared__ __align__(16) _Float16 Ah[64 * K];
    __shared__ __align__(16) _Float16 Bh[N * K];
    const int t = threadIdx.x;
    const int row0 = blockIdx.x * 64;

    // ---- stage A (64 x K), 4-half units, swizzled
#pragma unroll
    for (int q = t; q < 64 * K / 4; q += 256) {
        int r = q / (K / 4);
        int k4 = q % (K / 4);
        f16x4 v;
        int grow = row0 + r;
        if (grow < M) {
            if constexpr (sizeof(AT) == 4) {
                float4 f = *(const float4*)(A + (size_t)grow * K + k4 * 4);
                v[0] = (_Float16)f.x; v[1] = (_Float16)f.y;
                v[2] = (_Float16)f.z; v[3] = (_Float16)f.w;
            } else {
                v = *(const f16x4*)(A + (size_t)grow * K + k4 * 4);
            }
        } else {
            v[0] = v[1] = v[2] = v[3] = (_Float16)0.f;
        }
        int idx = r * K + (((k4 >> 1) ^ (r & 15)) << 3) + ((k4 & 1) << 2);
        *(f16x4*)&Ah[idx] = v;
    }
    // ---- stage B transposed (N x K), convert fp32->fp16
#pragma unroll
    for (int q = t; q < N * K / 4; q += 256) {
        int n = q & (N - 1);
        int k4 = q / N;
        f16x4 v;
#pragma unroll
        for (int i = 0; i < 4; ++i)
            v[i] = (_Float16)B[(size_t)(k4 * 4 + i) * N + n];
        int idx = n * K + (((k4 >> 1) ^ (n & 15)) << 3) + ((k4 & 1) << 2);
        *(f16x4*)&Bh[idx] = v;
    }
    __syncthreads();

    const int w = t >> 6;
    const int l = t & 63;
    const int lr = l & 15;
    const int g = l >> 4;

    f32x4 acc[4][CPW];
#pragma unroll
    for (int mt = 0; mt < 4; ++mt)
#pragma unroll
        for (int nt = 0; nt < CPW; ++nt)
            acc[mt][nt] = (f32x4){0.f, 0.f, 0.f, 0.f};

#pragma unroll
    for (int ks = 0; ks < K / 16; ++ks) {
        int k = ks * 16 + g * 4;
        f16x4 a[4], b[CPW];
#pragma unroll
        for (int mt = 0; mt < 4; ++mt) {
            int r = mt * 16 + lr;
            a[mt] = *(const f16x4*)&Ah[r * K + (((k >> 3) ^ (r & 15)) << 3) + (k & 7)];
        }
#pragma unroll
        for (int nt = 0; nt < CPW; ++nt) {
            int n = (w * CPW + nt) * 16 + lr;
            b[nt] = *(const f16x4*)&Bh[n * K + (((k >> 3) ^ (n & 15)) << 3) + (k & 7)];
        }
#pragma unroll
        for (int mt = 0; mt < 4; ++mt)
#pragma unroll
            for (int nt = 0; nt < CPW; ++nt)
                acc[mt][nt] = __builtin_amdgcn_mfma_f32_16x16x16f16(a[mt], b[nt],
                                                                   acc[mt][nt], 0, 0, 0);
    }
    // ---- epilogue: D row = 4*g+q, col = lr within each 16x16 tile
#pragma unroll
    for (int mt = 0; mt < 4; ++mt)
#pragma unroll
        for (int q = 0; q < 4; ++q) {
            int grow = row0 + mt * 16 + g * 4 + q;
            if (grow >= M) continue;
#pragma unroll
            for (int nt = 0; nt < CPW; ++nt) {
                int gcol = (w * CPW + nt) * 16 + lr;
                C[(size_t)grow * N + gcol] = (_Float16)acc[mt][nt][q];
            }
        }
}

// ---------------------------------------------------------------- alpha dots
__global__ __launch_bounds__(256) void alpha1_k(const __half* __restrict__ h1,
                                                const float* __restrict__ a_src,
                                                const float* __restrict__ a_dst,
                                                float* __restrict__ as1,
                                                float* __restrict__ ad1, int N) {
    int lane = threadIdx.x & 63;
    int n = blockIdx.x * 4 + (threadIdx.x >> 6);
    if (n >= N) return;
    const __half* hr = h1 + (size_t)n * 256;
#pragma unroll
    for (int h = 0; h < 4; ++h) {
        float hv = __half2float(hr[h * 64 + lane]);
        float s = hv * a_src[h * 64 + lane];
        float d = hv * a_dst[h * 64 + lane];
#pragma unroll
        for (int i = 0; i < 6; ++i) {
            s += __shfl_xor(s, 1 << i);
            d += __shfl_xor(d, 1 << i);
        }
        if (lane == 0) { as1[n * 4 + h] = s; ad1[n * 4 + h] = d; }
    }
}

__global__ __launch_bounds__(256) void alpha2_k(const __half* __restrict__ h2,
                                                const float* __restrict__ a_src,
                                                const float* __restrict__ a_dst,
                                                float* __restrict__ as2,
                                                float* __restrict__ ad2, int N) {
    int lane = threadIdx.x & 63;
    int n = blockIdx.x * 4 + (threadIdx.x >> 6);
    if (n >= N) return;
    float hv = __half2float(h2[(size_t)n * 64 + lane]);
    float s = hv * a_src[lane];
    float d = hv * a_dst[lane];
#pragma unroll
    for (int i = 0; i < 6; ++i) {
        s += __shfl_xor(s, 1 << i);
        d += __shfl_xor(d, 1 << i);
    }
    if (lane == 0) { as2[n] = s; ad2[n] = d; }
}

// ---------------------------------------------------------------- edge scores
__global__ __launch_bounds__(256) void e1_k(const int* __restrict__ edge_src,
                                            const int* __restrict__ edge_dst,
                                            const float* __restrict__ as1,
                                            const float* __restrict__ ad1,
                                            float* __restrict__ e_buf) {
    int p = blockIdx.x * 256 + threadIdx.x;
    if (p >= E_TOT) return;
    int s = edge_src[p], d = edge_dst[p];
    float4 es = *(const float4*)(as1 + (size_t)s * 4);
    float4 ed = *(const float4*)(ad1 + (size_t)d * 4);
    float4 e;
    e.x = lrelu(es.x + ed.x);
    e.y = lrelu(es.y + ed.y);
    e.z = lrelu(es.z + ed.z);
    e.w = lrelu(es.w + ed.w);
    *(float4*)(e_buf + (size_t)p * 4) = e;
}

__global__ __launch_bounds__(256) void e2_k(const int* __restrict__ edge_src,
                                            const int* __restrict__ edge_dst,
                                            const float* __restrict__ as2,
                                            const float* __restrict__ ad2,
                                            float* __restrict__ e_buf) {
    int p = blockIdx.x * 256 + threadIdx.x;
    if (p >= E_TOT) return;
    e_buf[p] = lrelu(as2[edge_src[p]] + ad2[edge_dst[p]]);
}

// ---------------------------------------------------------------- softmax + aggregate
__global__ __launch_bounds__(256) void agg1_k(const __half* __restrict__ h1,
                                              const float* __restrict__ e_buf,
                                              const int* __restrict__ edge_src,
                                              const int* __restrict__ offs,
                                              const int* __restrict__ counts,
                                              const float* __restrict__ b1,
                                              __half* __restrict__ out1, int N) {
    int lane = threadIdx.x & 63;
    int n = blockIdx.x * 4 + (threadIdx.x >> 6);
    if (n >= N) return;
    int start = offs[n];
    int end = start + counts[n];
    int h4 = lane & 3;
    float m = -1e30f, s = 0.f;
    for (int p = start + (lane >> 2); p < end; p += 16) {
        float e = e_buf[(size_t)p * 4 + h4];
        float nm = fmaxf(m, e);
        s = s * __expf(m - nm) + __expf(e - nm);
        m = nm;
    }
#pragma unroll
    for (int i = 0; i < 4; ++i) {                 // reduce over lanes with same head
        int msk = 4 << i;
        float om = __shfl_xor(m, msk);
        float os = __shfl_xor(s, msk);
        float nm = fmaxf(m, om);
        s = s * __expf(m - nm) + os * __expf(om - nm);
        m = nm;
    }
    float mh0 = __shfl(m, 0), mh1 = __shfl(m, 1), mh2 = __shfl(m, 2), mh3 = __shfl(m, 3);
    float rs0 = 1.f / (__shfl(s, 0) + 1e-16f);
    float rs1 = 1.f / (__shfl(s, 1) + 1e-16f);
    float rs2 = 1.f / (__shfl(s, 2) + 1e-16f);
    float rs3 = 1.f / (__shfl(s, 3) + 1e-16f);
    float acc0 = 0.f, acc1 = 0.f, acc2 = 0.f, acc3 = 0.f;
    int p = start;
    for (; p + 1 < end; p += 2) {                  // 2-edge unroll
        int s0 = edge_src[p], s1 = edge_src[p + 1];
        float4 ev0 = *(const float4*)(e_buf + (size_t)p * 4);
        float4 ev1 = *(const float4*)(e_buf + (size_t)(p + 1) * 4);
        const __half* r0 = h1 + (size_t)s0 * 256;
        const __half* r1 = h1 + (size_t)s1 * 256;
        float a00 = __half2float(r0[lane]);
        float a01 = __half2float(r0[64 + lane]);
        float a02 = __half2float(r0[128 + lane]);
        float a03 = __half2float(r0[192 + lane]);
        float a10 = __half2float(r1[lane]);
        float a11 = __half2float(r1[64 + lane]);
        float a12 = __half2float(r1[128 + lane]);
        float a13 = __half2float(r1[192 + lane]);
        float w00 = __expf(ev0.x - mh0) * rs0, w10 = __expf(ev1.x - mh0) * rs0;
        float w01 = __expf(ev0.y - mh1) * rs1, w11 = __expf(ev1.y - mh1) * rs1;
        float w02 = __expf(ev0.z - mh2) * rs2, w12 = __expf(ev1.z - mh2) * rs2;
        float w03 = __expf(ev0.w - mh3) * rs3, w13 = __expf(ev1.w - mh3) * rs3;
        acc0 += a00 * w00 + a10 * w10;
        acc1 += a01 * w01 + a11 * w11;
        acc2 += a02 * w02 + a12 * w12;
        acc3 += a03 * w03 + a13 * w13;
    }
    if (p < end) {
        int s0 = edge_src[p];
        float4 ev0 = *(const float4*)(e_buf + (size_t)p * 4);
        const __half* r0 = h1 + (size_t)s0 * 256;
        acc0 += __half2float(r0[lane])       * (__expf(ev0.x - mh0) * rs0);
        acc1 += __half2float(r0[64 + lane])  * (__expf(ev0.y - mh1) * rs1);
        acc2 += __half2float(r0[128 + lane]) * (__expf(ev0.z - mh2) * rs2);
        acc3 += __half2float(r0[192 + lane]) * (__expf(ev0.w - mh3) * rs3);
    }
    __half* o = out1 + (size_t)n * 256;
    o[lane]       = __float2half(fmaxf(acc0 + b1[lane], 0.f));
    o[64 + lane]  = __float2half(fmaxf(acc1 + b1[64 + lane], 0.f));
    o[128 + lane] = __float2half(fmaxf(acc2 + b1[128 + lane], 0.f));
    o[192 + lane] = __float2half(fmaxf(acc3 + b1[192 + lane], 0.f));
}

__global__ __launch_bounds__(256) void agg2_k(const __half* __restrict__ h2,
                                              const float* __restrict__ e_buf,
                                              const int* __restrict__ edge_src,
                                              const int* __restrict__ offs,
                                              const int* __restrict__ counts,
                                              const float* __restrict__ b2,
                                              float* __restrict__ out2, int N) {
    int lane = threadIdx.x & 63;
    int n = blockIdx.x * 4 + (threadIdx.x >> 6);
    if (n >= N) return;
    int start = offs[n];
    int end = start + counts[n];
    float m = -1e30f, s = 0.f;
    for (int p = start + lane; p < end; p += 64) {
        float e = e_buf[p];
        float nm = fmaxf(m, e);
        s = s * __expf(m - nm) + __expf(e - nm);
        m = nm;
    }
#pragma unroll
    for (int i = 0; i < 6; ++i) {
        int msk = 1 << i;
        float om = __shfl_xor(m, msk);
        float os = __shfl_xor(s, msk);
        float nm = fmaxf(m, om);
        s = s * __expf(m - nm) + os * __expf(om - nm);
        m = nm;
    }
    float rs = 1.f / (s + 1e-16f);
    float acc = 0.f;
    int p = start;
    for (; p + 1 < end; p += 2) {
        int s0 = edge_src[p], s1 = edge_src[p + 1];
        float e0 = e_buf[p], e1 = e_buf[p + 1];
        float v0 = __half2float(h2[(size_t)s0 * 64 + lane]);
        float v1 = __half2float(h2[(size_t)s1 * 64 + lane]);
        acc += v0 * (__expf(e0 - m) * rs) + v1 * (__expf(e1 - m) * rs);
    }
    if (p < end) {
        acc += __half2float(h2[(size_t)edge_src[p] * 64 + lane]) * (__expf(e_buf[p] - m) * rs);
    }
    out2[(size_t)n * 64 + lane] = fmaxf(acc + b2[lane], 0.f);
}

// ---------------------------------------------------------------- classifier head
__global__ __launch_bounds__(256) void cls_k(const float* __restrict__ hin,
                                             const float* __restrict__ Wc1,
                                             const float* __restrict__ bc1,
                                             const float* __restrict__ Wc2,
                                             const float* __restrict__ bc2,
                                             float* __restrict__ out, int N) {
    __shared__ float W1s[64 * 32];
    __shared__ float W2s[64];
    __shared__ float b1s[32];
    __shared__ float b2s[2];
    __shared__ float z[8][33];
    int t = threadIdx.x;
    for (int i = t; i < 2048; i += 256) W1s[i] = Wc1[i];
    if (t < 64) W2s[t] = Wc2[t];
    if (t < 32) b1s[t] = bc1[t];
    if (t < 2)  b2s[t] = bc2[t];
    __syncthreads();
    int nl = t >> 5, j = t & 31;
    int n = blockIdx.x * 8 + nl;
    float acc = b1s[j];
    if (n < N) {
        const float* hr = hin + (size_t)n * 64;
#pragma unroll 8
        for (int l = 0; l < 64; ++l) acc += hr[l] * W1s[l * 32 + j];
    }
    z[nl][j] = fmaxf(acc, 0.f);
    __syncthreads();
    if (j < 2 && n < N) {
        float o = b2s[j];
#pragma unroll
        for (int q = 0; q < 32; ++q) o += z[nl][q] * W2s[q * 2 + j];
        out[(size_t)n * 2 + j] = o;
    }
}

// ---------------------------------------------------------------- launch
extern "C" void kernel_launch(void* const* d_in, const int* in_sizes, int n_in,
                              void* d_out, int out_size, void* d_ws, size_t ws_size,
                              hipStream_t stream) {
    const float* x      = (const float*)d_in[0];
    const int*   ei     = (const int*)d_in[1];
    const float* W1     = (const float*)d_in[2];
    const float* a_src1 = (const float*)d_in[3];
    const float* a_dst1 = (const float*)d_in[4];
    const float* b1     = (const float*)d_in[5];
    const float* W2     = (const float*)d_in[6];
    const float* a_src2 = (const float*)d_in[7];
    const float* a_dst2 = (const float*)d_in[8];
    const float* b2     = (const float*)d_in[9];
    const float* Wc1    = (const float*)d_in[10];
    const float* bc1    = (const float*)d_in[11];
    const float* Wc2    = (const float*)d_in[12];
    const float* bc2    = (const float*)d_in[13];

    char* ws = (char*)d_ws;
    size_t off = 0;
    auto alloc = [&](size_t bytes) -> void* {
        void* p = ws + off;
        off += (bytes + 255) & ~(size_t)255;
        return p;
    };
    int*      counts   = (int*)alloc((size_t)N_NODES * 4);
    int*      cursor   = (int*)alloc((size_t)N_NODES * 4);
    int*      offs     = (int*)alloc((size_t)N_NODES * 4);
    int*      chunks   = (int*)alloc(256);
    int*      edge_src = (int*)alloc((size_t)E_TOT * 4);
    int*      edge_dst = (int*)alloc((size_t)E_TOT * 4);
    float*    e_buf    = (float*)alloc((size_t)E_TOT * 4 * 4);
    float*    as1      = (float*)alloc((size_t)N_NODES * 16);
    float*    ad1      = (float*)alloc((size_t)N_NODES * 16);
    float*    as2      = (float*)alloc((size_t)N_NODES * 4);
    float*    ad2      = (float*)alloc((size_t)N_NODES * 4);
    __half*   h1h      = (__half*)alloc((size_t)N_NODES * 256 * 2);  // fp16 h1; slot reused as fp16 h2
    __half*   out1h    = (__half*)alloc((size_t)N_NODES * 256 * 2);  // fp16 out1
    float*    out2     = (float*)alloc((size_t)N_NODES * 64 * 4);    // fp32 (cls input)
    __half*   h2h  = h1h;   // 6.4 MB fp16, fits in the 25.6 MB slot; h1 dead after agg1

    const int EB = (E_TOT + 255) / 256;
    const int NCH = (N_NODES + 1023) / 1024;  // 49
    const int MB = (N_NODES + 63) / 64;       // 782

    hipMemsetAsync(counts, 0, (size_t)N_NODES * 4, stream);
    hipMemsetAsync(cursor, 0, (size_t)N_NODES * 4, stream);

    count_k<<<EB, 256, 0, stream>>>(ei, counts);
    scanA<<<NCH, 1024, 0, stream>>>(counts, offs, chunks, N_NODES);
    scanB<<<1, 64, 0, stream>>>(chunks, NCH);
    scanC<<<NCH, 1024, 0, stream>>>(offs, chunks, N_NODES);
    scatter_k<<<EB, 256, 0, stream>>>(ei, offs, cursor, edge_src, edge_dst);

    gemm_mfma<128, 256, 4, float><<<MB, 256, 0, stream>>>(x, W1, (_Float16*)h1h, N_NODES);
    alpha1_k<<<(N_NODES + 3) / 4, 256, 0, stream>>>(h1h, a_src1, a_dst1, as1, ad1, N_NODES);
    e1_k<<<EB, 256, 0, stream>>>(edge_src, edge_dst, as1, ad1, e_buf);
    agg1_k<<<(N_NODES + 3) / 4, 256, 0, stream>>>(h1h, e_buf, edge_src, offs, counts, b1, out1h, N_NODES);

    gemm_mfma<256, 64, 1, _Float16><<<MB, 256, 0, stream>>>((const _Float16*)out1h, W2,
                                                            (_Float16*)h2h, N_NODES);
    alpha2_k<<<(N_NODES + 3) / 4, 256, 0, stream>>>(h2h, a_src2, a_dst2, as2, ad2, N_NODES);
    e2_k<<<EB, 256, 0, stream>>>(edge_src, edge_dst, as2, ad2, e_buf);
    agg2_k<<<(N_NODES + 3) / 4, 256, 0, stream>>>(h2h, e_buf, edge_src, offs, counts, b2, out2, N_NODES);

    cls_k<<<N_NODES / 8, 256, 0, stream>>>(out2, Wc1, bc1, Wc2, bc2, (float*)d_out, N_NODES);
}